// Round 9
// baseline (150.540 us; speedup 1.0000x reference)
//
#include <hip/hip_runtime.h>
#include <math.h>

// KTVLoss: inputs out_l, out_r, input_i : (8,3,512,512) fp32. Output: 1 fp32 scalar.
//
// Sx = 10x10 box sum of |dI/dh| (502x503), Sy = box sum of |dI/dw| (503x502).
// Reference pairs them by FLAT index: Sx(i,j) with Sy(i,i+j) if i+j<502 else
// Sy(i+1,i+j-502). ratio = (SxL+SyL+SxR+SyR)/(SxI+SyI+1e-4), mean over 24*502*503.
// grad part (fp32): mean|GxL+GxR-GxI| + mean|GyL+GyR-GyI| over 24*511*512 each.
// norm part carries 1e-4 weight -> packed f16 (abs err ~1e-5; validated R4-R8).
//
// R9 structure (R7 single-pass work + R8 wave-local halo, 2 barriers/band):
//  - One block per (image, band of RB=20 Sx rows); 512 thr = 1/col; 624 blocks.
//  - Each wave owns a 64-col strip + loads its own 10-col halo -> horizontal
//    10-window fully wave-local (DPP prefix scans, validated R8).
//  - Single 30-step stream computes BOTH vertical rings (Sy, Sx) per step.
//    Completed Sy rows -> flat 21-row LDS array. Sx rows -> snapX[10] regs
//    (thread-private => race-free).
//  - Ratio bursts after chunk barriers: barrier1 then rows 0..9 (Sy 0..10,
//    disjoint from chunk2's writes 11..20), barrier2 then rows 10..19.
//  - 2-row-deep register prefetch hides load latency.
// VGPR cap law (R4-R7): cap = 256/min_waves; (512,2) -> 128, no spill.

namespace {

constexpr int H = 512, W = 512;
constexpr int CX = 503;          // Sx cols (Sy has 503 rows)
constexpr int CY = 502;          // Sy cols (Sx has 502 rows)
constexpr int RB = 20;           // Sx rows per band
constexpr int NBANDS = 26;       // ceil(502/20)
constexpr int NIMG = 24;
constexpr int NBLOCKS = NIMG * NBANDS;   // 624

typedef __fp16 h2 __attribute__((ext_vector_type(2)));

__device__ __forceinline__ int h2i(h2 v) { int r; __builtin_memcpy(&r, &v, 4); return r; }
__device__ __forceinline__ h2 i2h(int v) { h2 r; __builtin_memcpy(&r, &v, 4); return r; }

template <int C, int RM>
__device__ __forceinline__ int dppmov(int v) {
  return __builtin_amdgcn_update_dpp(0, v, C, RM, 0xf, true);
}
// full 64-lane inclusive prefix sum of a f16x2 pack (pure VALU)
__device__ __forceinline__ h2 scan64(h2 v) {
  v += i2h(dppmov<0x111, 0xf>(h2i(v)));  // row_shr:1
  v += i2h(dppmov<0x112, 0xf>(h2i(v)));  // row_shr:2
  v += i2h(dppmov<0x114, 0xf>(h2i(v)));  // row_shr:4
  v += i2h(dppmov<0x118, 0xf>(h2i(v)));  // row_shr:8
  v += i2h(dppmov<0x142, 0xa>(h2i(v)));  // row_bcast15 -> rows 1,3
  v += i2h(dppmov<0x143, 0xc>(h2i(v)));  // row_bcast31 -> rows 2,3
  return v;
}
// prefix valid for lanes 0..15 (halo uses lanes 0..8 only)
__device__ __forceinline__ h2 scan9(h2 v) {
  v += i2h(dppmov<0x111, 0xf>(h2i(v)));
  v += i2h(dppmov<0x112, 0xf>(h2i(v)));
  v += i2h(dppmov<0x114, 0xf>(h2i(v)));
  v += i2h(dppmov<0x118, 0xf>(h2i(v)));
  return v;
}
__device__ __forceinline__ float wshl1(float v) {  // lane i <- lane i+1
  return __int_as_float(__builtin_amdgcn_update_dpp(0, __float_as_int(v), 0x130, 0xf, 0xf, true));
}

}  // namespace

// horizontal 10-window: E main pack, E2 halo pack (lanes 0..8)  [validated R8]
#define HWIN(E, E2, OUT)                                                        \
  h2 OUT;                                                                       \
  {                                                                             \
    const h2 A_ = scan64(E), B_ = scan9(E2);                                    \
    const h2 Aex_ = i2h(dppmov<0x138, 0xf>(h2i(A_)));  /* A[lane-1] */          \
    const h2 T_ = i2h(__builtin_amdgcn_readlane(h2i(A_), 63));                  \
    const h2 t9_ = i2h(__shfl(h2i(A_), lane + 9));                              \
    const h2 t2_ = i2h(__shfl(h2i(B_), lane - 55));                             \
    OUT = (lane <= 54 ? t9_ : T_ + t2_) - Aex_;                                 \
  }

// one streaming step; S (step) and U (= S%10) are literals
#define STEP(S, U)                                                              \
  {                                                                             \
    constexpr int s_ = (S);                                                     \
    const int r = i0 + s_;                                                      \
    const float xl = cL, xr = cR, xi = cI;                                      \
    const float bl = hL, br = hR, bi = hI;                                      \
    /* gx row r-1 (main + halo) */                                              \
    const float gxl = xl - pvL, gxr = xr - pvR, gxi = xi - pvI;                 \
    const float qxl = bl - bpL, qxr = br - bpR, qxi = bi - bpI;                 \
    pvL = xl; pvR = xr; pvI = xi; bpL = bl; bpR = br; bpI = bi;                 \
    cL = n1L; cR = n1R; cI = n1I; hL = m1L; hR = m1R; hI = m1I;                 \
    if (r + 2 < H) { /* prefetch row r+2 (wave-uniform guard) */                \
      n1L = pL[offN]; n1R = pR[offN]; n1I = pI[offN];                           \
      if (vok) { m1L = pL[offN + 64]; m1R = pR[offN + 64]; m1I = pI[offN + 64]; } \
      offN += W;                                                                \
    }                                                                           \
    /* gy row r (main + halo) */                                                \
    float nxl = wshl1(xl), nxr = wshl1(xr), nxi = wshl1(xi);                    \
    const float f0l = __shfl(bl, 0), f0r = __shfl(br, 0), f0i = __shfl(bi, 0); \
    if (lane == 63) { nxl = f0l; nxr = f0r; nxi = f0i; }                        \
    const float gyl = nxl - xl, gyr = nxr - xr, gyi = nxi - xi;                 \
    const float qyl = wshl1(bl) - bl, qyr = wshl1(br) - br, qyi = wshl1(bi) - bi; \
    if (r < gyEnd && col < W - 1) accGY += fabsf(gyl + gyr - gyi);              \
    if (s_ > 0 && (r - 1) < gxEnd) accGX += fabsf(gxl + gxr - gxi);             \
    const bool rv = (r < H);                                                    \
    const bool evY = rv && (col < W - 1);                                       \
    const bool evX = rv && (s_ > 0);                                            \
    const float yn = evY ? (fabsf(gyl) + fabsf(gyr)) : 0.f;                     \
    const float yd = evY ? fabsf(gyi) : 0.f;                                    \
    const float xn = evX ? (fabsf(gxl) + fabsf(gxr)) : 0.f;                     \
    const float xd = evX ? fabsf(gxi) : 0.f;                                    \
    const bool e2Y = rv && hok;                                                 \
    const bool e2X = rv && hok && (s_ > 0);                                     \
    const float wn = e2Y ? (fabsf(qyl) + fabsf(qyr)) : 0.f;                     \
    const float wd = e2Y ? fabsf(qyi) : 0.f;                                    \
    const float vn = e2X ? (fabsf(qxl) + fabsf(qxr)) : 0.f;                     \
    const float vd = e2X ? fabsf(qxi) : 0.f;                                    \
    const h2 Y = __builtin_amdgcn_cvt_pkrtz(yn, yd);                            \
    const h2 X = __builtin_amdgcn_cvt_pkrtz(xn, xd);                            \
    const h2 Y2 = __builtin_amdgcn_cvt_pkrtz(wn, wd);                           \
    const h2 X2 = __builtin_amdgcn_cvt_pkrtz(vn, vd);                           \
    HWIN(Y, Y2, hY)                                                             \
    HWIN(X, X2, hX)                                                             \
    runY += hY - histY[U]; histY[U] = hY;                                       \
    runX += hX - histX[U]; histX[U] = hX;                                       \
    snapX[U] = runX;             /* Sx row r-10 when s_>=10 */                  \
    if (s_ >= 9) {               /* Sy row r-9 -> LDS slot s_-9 (0..20) */      \
      if (col < CY) syLDS[s_ - 9][col] = h2i(runY);                             \
    }                                                                           \
  }

// ratio for Sx row i0+K (K literal); snapX slot K%10; Sy slots K / K+1
#define RATIO(K)                                                                \
  {                                                                             \
    const int iX = i0 + (K);                                                    \
    if (iX < sxEnd && col < CX) {                                               \
      int jy = iX + col, slot = (K);                                            \
      if (jy >= CY) { jy -= CY; ++slot; }                                       \
      const h2 sy = i2h(syLDS[slot][jy]);                                       \
      const h2 sx = snapX[(K) % 10];                                            \
      const float num = (float)sx.x + (float)sy.x;                              \
      const float den = (float)sx.y + (float)sy.y + 1e-4f;                      \
      accN += num * __builtin_amdgcn_rcpf(den);                                 \
    }                                                                           \
  }

__global__ __launch_bounds__(512, 2) void ktv_main(const float* __restrict__ L,
                                                   const float* __restrict__ R,
                                                   const float* __restrict__ I,
                                                   double* __restrict__ partial) {
  const int blk = blockIdx.x;
  const int img = blk / NBANDS;
  const int band = blk % NBANDS;
  const int i0 = band * RB;
  const int j = threadIdx.x;
  const int lane = j & 63;
  const int wv = j >> 6;
  const int col = j;
  const bool vok = (lane <= 9) && (wv < 7);  // halo loader lanes (cols c+64..c+73)
  const bool hok = (lane <= 8) && (wv < 7);  // halo window-contributing lanes

  const bool lastb = (band == NBANDS - 1);
  const int gyEnd = lastb ? H : (i0 + RB);        // Gy rows owned [i0, gyEnd)
  const int gxEnd = lastb ? (H - 1) : (i0 + RB);  // Gx rows owned [i0, gxEnd)
  const int sxEnd = lastb ? CY : (i0 + RB);       // Sx rows owned [i0, sxEnd)

  const size_t base = (size_t)img * (H * W);
  const float* pL = L + base;
  const float* pR = R + base;
  const float* pI = I + base;

  __shared__ int syLDS[RB + 1][CY];   // Sy rows i0..i0+20 (f16x2 n,d) = 42.2 KB
  __shared__ float redN[8], redGX[8], redGY[8];

  h2 histY[10], histX[10], snapX[10];
#pragma unroll
  for (int t = 0; t < 10; ++t) {
    histY[t] = (h2)(__fp16)0; histX[t] = (h2)(__fp16)0; snapX[t] = (h2)(__fp16)0;
  }
  h2 runY = (h2)(__fp16)0, runX = (h2)(__fp16)0;
  float accN = 0.f, accGX = 0.f, accGY = 0.f;

  // prologue: rows i0 (cur) and i0+1 (next); halo same
  int offN = i0 * W + col;
  float cL = pL[offN], cR = pR[offN], cI = pI[offN];
  float hL = 0.f, hR = 0.f, hI = 0.f;
  if (vok) { hL = pL[offN + 64]; hR = pR[offN + 64]; hI = pI[offN + 64]; }
  float n1L = pL[offN + W], n1R = pR[offN + W], n1I = pI[offN + W];
  float m1L = 0.f, m1R = 0.f, m1I = 0.f;
  if (vok) { m1L = pL[offN + W + 64]; m1R = pR[offN + W + 64]; m1I = pI[offN + W + 64]; }
  offN += 2 * W;
  float pvL = 0.f, pvR = 0.f, pvI = 0.f;     // gx at s=0 is masked
  float bpL = 0.f, bpR = 0.f, bpI = 0.f;

  // chunk 0 + chunk 1 (steps 0..19)
  STEP(0, 0)  STEP(1, 1)  STEP(2, 2)  STEP(3, 3)  STEP(4, 4)
  STEP(5, 5)  STEP(6, 6)  STEP(7, 7)  STEP(8, 8)  STEP(9, 9)
  STEP(10, 0) STEP(11, 1) STEP(12, 2) STEP(13, 3) STEP(14, 4)
  STEP(15, 5) STEP(16, 6) STEP(17, 7) STEP(18, 8) STEP(19, 9)

  __syncthreads();  // barrier 1: Sy rows 0..10 + snapshots 0..9 complete

  RATIO(0) RATIO(1) RATIO(2) RATIO(3) RATIO(4)
  RATIO(5) RATIO(6) RATIO(7) RATIO(8) RATIO(9)
  // (fast waves may enter chunk 2 writing Sy rows 11..20 -- disjoint, race-free)

  // chunk 2 (steps 20..29)
  STEP(20, 0) STEP(21, 1) STEP(22, 2) STEP(23, 3) STEP(24, 4)
  STEP(25, 5) STEP(26, 6) STEP(27, 7) STEP(28, 8) STEP(29, 9)

  __syncthreads();  // barrier 2: Sy rows 11..20 + snapshots 10..19 complete

  RATIO(10) RATIO(11) RATIO(12) RATIO(13) RATIO(14)
  RATIO(15) RATIO(16) RATIO(17) RATIO(18) RATIO(19)

  // block reduction
#pragma unroll
  for (int o2 = 32; o2 > 0; o2 >>= 1) {
    accN  += __shfl_down(accN, o2);
    accGX += __shfl_down(accGX, o2);
    accGY += __shfl_down(accGY, o2);
  }
  if (lane == 0) { redN[wv] = accN; redGX[wv] = accGX; redGY[wv] = accGY; }
  __syncthreads();
  if (j == 0) {
    float n = 0.f, gx = 0.f, gy = 0.f;
#pragma unroll
    for (int w2 = 0; w2 < 8; ++w2) { n += redN[w2]; gx += redGX[w2]; gy += redGY[w2]; }
    double* p = partial + (size_t)blk * 3;
    p[0] = (double)n; p[1] = (double)gx; p[2] = (double)gy;
  }
}

__global__ __launch_bounds__(64) void ktv_reduce(const double* __restrict__ partial,
                                                 float* __restrict__ out) {
  double n = 0.0, gx = 0.0, gy = 0.0;
  for (int i = threadIdx.x; i < NBLOCKS; i += 64) {
    const double* p = partial + (size_t)i * 3;
    n += p[0]; gx += p[1]; gy += p[2];
  }
#pragma unroll
  for (int o2 = 32; o2 > 0; o2 >>= 1) {
    n  += __shfl_down(n, o2);
    gx += __shfl_down(gx, o2);
    gy += __shfl_down(gy, o2);
  }
  if (threadIdx.x == 0) {
    const double norm_loss = n / 6060144.0;          // 24*502*503
    const double grad_loss = (gx + gy) / 6279168.0;  // 24*511*512
    out[0] = (float)(1e-4 * norm_loss + grad_loss);
  }
}

extern "C" void kernel_launch(void* const* d_in, const int* in_sizes, int n_in,
                              void* d_out, int out_size, void* d_ws, size_t ws_size,
                              hipStream_t stream) {
  (void)in_sizes; (void)n_in; (void)out_size; (void)ws_size;
  const float* L = (const float*)d_in[0];
  const float* R = (const float*)d_in[1];
  const float* I = (const float*)d_in[2];
  double* partial = (double*)d_ws;   // NBLOCKS*3 doubles = 14976 B
  float* out = (float*)d_out;

  hipLaunchKernelGGL(ktv_main, dim3(NBLOCKS), dim3(512), 0, stream, L, R, I, partial);
  hipLaunchKernelGGL(ktv_reduce, dim3(1), dim3(64), 0, stream, partial, out);
}

// Round 10
// 134.563 us; speedup vs baseline: 1.1187x; 1.1187x over previous
//
#include <hip/hip_runtime.h>
#include <math.h>

// KTVLoss: inputs out_l, out_r, input_i : (8,3,512,512) fp32. Output: 1 fp32 scalar.
//
// Sx = 10x10 box sum of |dI/dh| (502x503), Sy = box sum of |dI/dw| (503x502).
// Reference pairs them by FLAT index: Sx(i,j) with Sy(i,i+j) if i+j<502 else
// Sy(i+1,i+j-502). ratio = (SxL+SyL+SxR+SyR)/(SxI+SyI+1e-4), mean over 24*502*503.
// grad part (fp32): mean|GxL+GxR-GxI| + mean|GyL+GyR-GyI| over 24*511*512 each.
// norm part carries 1e-4 weight -> packed f16 (abs err ~1e-5; validated R4-R9).
//
// Structure = R7 (best so far, 57.6 us): one block per (image, band of RB=24
// Sx rows); 512 threads = 1/col; 504 blocks. Horizontal 10-window via
// full-wave DPP prefix scan on packed f16; wave-boundary 9 lanes patched via
// tiny LDS bnd array. Vertical 10-window via f16x2 register rings (35
// fully-unrolled steps => static slots). Sy rows in depth-4 LDS ring;
// Sx<->Sy ratio read one step delayed.
//
// R10 change (single variable vs R7): the per-step barrier is a RAW
// s_waitcnt(lgkmcnt(0)) + s_barrier instead of __syncthreads().
// __syncthreads drains vmcnt(0) too, which serialized the global prefetch
// round-trip into every one of the 35 steps (the m97 barrier-drain stall).
// The barrier only guards LDS (bnd/syring) => lgkmcnt(0) suffices; global
// prefetches stay in flight across the barrier.
// 0xC07F = vmcnt 63 (max, [3:0]=0xF,[15:14]=3) | expcnt 7 ([6:4]) | lgkmcnt 0.
//
// VGPR cap law (R4-R7): cap = 256/min_waves; (512,2) -> 128, no spill @ 120.

namespace {

constexpr int H = 512, W = 512;
constexpr int CX = W - 10 + 1;   // 503 Sx cols (Sy has 503 rows)
constexpr int CY = W - 10;       // 502 Sy cols
constexpr int RB = 24;           // Sx rows per band
constexpr int NBANDS = (CY + RB - 1) / RB;   // 21
constexpr int NIMG = 24;
constexpr int NBLOCKS = NIMG * NBANDS;       // 504

typedef __fp16 h2 __attribute__((ext_vector_type(2)));

__device__ __forceinline__ int h2i(h2 v) { int r; __builtin_memcpy(&r, &v, 4); return r; }
__device__ __forceinline__ h2 i2h(int v) { h2 r; __builtin_memcpy(&r, &v, 4); return r; }

template <int C, int RM>
__device__ __forceinline__ int dppmov(int v) {
  return __builtin_amdgcn_update_dpp(0, v, C, RM, 0xf, true);
}
// full 64-lane inclusive prefix sum of a f16x2 pack (pure VALU)
__device__ __forceinline__ h2 scan64(h2 v) {
  v += i2h(dppmov<0x111, 0xf>(h2i(v)));  // row_shr:1
  v += i2h(dppmov<0x112, 0xf>(h2i(v)));  // row_shr:2
  v += i2h(dppmov<0x114, 0xf>(h2i(v)));  // row_shr:4
  v += i2h(dppmov<0x118, 0xf>(h2i(v)));  // row_shr:8
  v += i2h(dppmov<0x142, 0xa>(h2i(v)));  // row_bcast15 -> rows 1,3
  v += i2h(dppmov<0x143, 0xc>(h2i(v)));  // row_bcast31 -> rows 2,3
  return v;
}
__device__ __forceinline__ float wshl1(float v) {  // lane i <- lane i+1
  return __int_as_float(__builtin_amdgcn_update_dpp(0, __float_as_int(v), 0x130, 0xf, 0xf, true));
}

// LDS-only barrier: waits ds ops (lgkmcnt 0) but leaves global loads in flight.
__device__ __forceinline__ void kbarrier() {
  __builtin_amdgcn_s_waitcnt(0xC07F);   // lgkmcnt(0), vmcnt(max), expcnt(max)
  __builtin_amdgcn_s_barrier();
}

}  // namespace

// One streaming step; S (step) and U (ring slot = S%10) are literals.
#define STEP(S, U)                                                                \
  {                                                                               \
    constexpr int s_ = (S);                                                       \
    const int r = i0 + s_;                                                        \
    const float xl = nL, xr = nR, xi = nI;                                        \
    const float x1l = mL, x1r = mR, x1i = mI;                                     \
    if (r + 1 < H) { /* prefetch next row (wave-uniform guard) */                 \
      nL = pL[offN]; nR = pR[offN]; nI = pI[offN];                                \
      if (lastlane) { mL = pL[offN + 1]; mR = pR[offN + 1]; mI = pI[offN + 1]; }  \
      offN += W;                                                                  \
    }                                                                             \
    float nxl = wshl1(xl), nxr = wshl1(xr), nxi = wshl1(xi);                      \
    if (lastlane) { nxl = x1l; nxr = x1r; nxi = x1i; }                            \
    const float gyl = nxl - xl, gyr = nxr - xr, gyi = nxi - xi;                   \
    const float gxl = xl - prevL, gxr = xr - prevR, gxi = xi - prevI;             \
    prevL = xl; prevR = xr; prevI = xi;                                           \
    if (r < gyEnd && j < W - 1) accGY += fabsf(gyl + gyr - gyi);                  \
    if (s_ > 0 && (r - 1) < gxEnd) accGX += fabsf(gxl + gxr - gxi);               \
    float yn = fabsf(gyl) + fabsf(gyr), yd = fabsf(gyi);                          \
    float xn = fabsf(gxl) + fabsf(gxr), xd = fabsf(gxi);                          \
    if (j == W - 1) { yn = 0.f; yd = 0.f; }                                       \
    if (r >= H) { yn = 0.f; yd = 0.f; xn = 0.f; xd = 0.f; }                       \
    const h2 Y = __builtin_amdgcn_cvt_pkrtz(yn, yd);                              \
    h2 X = (h2)(__fp16)0;                                                         \
    if (s_ != 0) X = __builtin_amdgcn_cvt_pkrtz(xn, xd);                          \
    const h2 AY = scan64(Y), AX = scan64(X);                                      \
    const h2 eY = i2h(dppmov<0x138, 0xf>(h2i(AY)));  /* A[lane-1], wave_shr:1 */  \
    const h2 eX = i2h(dppmov<0x138, 0xf>(h2i(AX)));                               \
    const h2 TY = i2h(__builtin_amdgcn_readlane(h2i(AY), 63));                    \
    const h2 TX = i2h(__builtin_amdgcn_readlane(h2i(AX), 63));                    \
    h2 hY = i2h(__shfl(h2i(AY), lane9)) - eY;        /* A[lane+9]-A[lane-1] */    \
    h2 hX = i2h(__shfl(h2i(AX), lane9)) - eX;                                     \
    const h2 pY = TY - eY, pX = TX - eX;                                          \
    if (lane <= 8) bnd[s_ & 1][wv][lane] = make_int2(h2i(AY), h2i(AX));           \
    kbarrier();                                                                   \
    if (patch) { /* lanes 55..63: window spills into next wave */                 \
      const int2 Ap = bnd[s_ & 1][wv + 1][lane - 55];                             \
      hY = i2h(Ap.x) + pY;                                                        \
      hX = i2h(Ap.y) + pX;                                                        \
    }                                                                             \
    if (s_ >= 11) { /* runX pre-update == Sx row r-11; Sy rows r-11,r-10 ready */ \
      const int iX = r - 11;                                                      \
      if (iX < sxEnd && j < CX) {                                                 \
        int jy = iX + j, rw = iX;                                                 \
        if (jy >= CY) { jy -= CY; ++rw; }                                         \
        const h2 sy = i2h(syring[rw & 3][jy]);                                    \
        const float num = (float)runX.x + (float)sy.x;                            \
        const float den = (float)runX.y + (float)sy.y + 1e-4f;                    \
        accN += num * __builtin_amdgcn_rcpf(den);                                 \
      }                                                                           \
    }                                                                             \
    runY += hY - histY[U]; histY[U] = hY;                                         \
    runX += hX - histX[U]; histX[U] = hX;                                         \
    if (s_ >= 9) {                                                                \
      const int iY = r - 9;                                                       \
      if (iY <= sxEnd && j < CY) syring[iY & 3][j] = h2i(runY);                   \
    }                                                                             \
  }

__global__ __launch_bounds__(512, 2) void ktv_main(const float* __restrict__ L,
                                                   const float* __restrict__ R,
                                                   const float* __restrict__ I,
                                                   double* __restrict__ partial) {
  const int blk = blockIdx.x;
  const int img = blk / NBANDS;
  const int band = blk % NBANDS;
  const int i0 = band * RB;
  const int j = threadIdx.x;  // column
  const int lane = j & 63;
  const int wv = j >> 6;
  const int lane9 = lane + 9;
  const bool lastlane = (lane == 63) && (j < W - 1);
  const bool patch = (lane >= 55) && (wv < 7);

  const bool lastb = (band == NBANDS - 1);
  const int gyEnd = lastb ? H : (i0 + RB);        // Gy rows owned: [i0, gyEnd)
  const int gxEnd = lastb ? (H - 1) : (i0 + RB);  // Gx rows owned: [i0, gxEnd)
  const int sxEnd = lastb ? CY : (i0 + RB);       // Sx rows owned: [i0, sxEnd)

  const size_t base = (size_t)img * (H * W);
  const float* pL = L + base;
  const float* pR = R + base;
  const float* pI = I + base;

  __shared__ int syring[4][CY];    // completed Sy rows (f16x2 n,d), depth-4 ring
  __shared__ int2 bnd[2][8][9];    // per-wave lanes 0..8 scan prefix (Y,X packs)
  __shared__ float redN[8], redGX[8], redGY[8];

  h2 histY[10], histX[10];
#pragma unroll
  for (int t = 0; t < 10; ++t) { histY[t] = (h2)(__fp16)0; histX[t] = (h2)(__fp16)0; }
  h2 runY = (h2)(__fp16)0, runX = (h2)(__fp16)0;
  float accN = 0.f, accGX = 0.f, accGY = 0.f;
  float prevL = 0.f, prevR = 0.f, prevI = 0.f;

  // prologue: load row i0 (+ lane-63 col j+1 patch values)
  int offN = i0 * W + j;
  float nL = pL[offN], nR = pR[offN], nI = pI[offN];
  float mL = 0.f, mR = 0.f, mI = 0.f;
  if (lastlane) { mL = pL[offN + 1]; mR = pR[offN + 1]; mI = pI[offN + 1]; }
  offN += W;

  // 35 fully-unrolled steps (static ring slots, static bnd/syring indices)
  STEP(0, 0)  STEP(1, 1)  STEP(2, 2)  STEP(3, 3)  STEP(4, 4)
  STEP(5, 5)  STEP(6, 6)  STEP(7, 7)  STEP(8, 8)  STEP(9, 9)
  STEP(10, 0) STEP(11, 1) STEP(12, 2) STEP(13, 3) STEP(14, 4)
  STEP(15, 5) STEP(16, 6) STEP(17, 7) STEP(18, 8) STEP(19, 9)
  STEP(20, 0) STEP(21, 1) STEP(22, 2) STEP(23, 3) STEP(24, 4)
  STEP(25, 5) STEP(26, 6) STEP(27, 7) STEP(28, 8) STEP(29, 9)
  STEP(30, 0) STEP(31, 1) STEP(32, 2) STEP(33, 3) STEP(34, 4)

  // block reduction
#pragma unroll
  for (int o2 = 32; o2 > 0; o2 >>= 1) {
    accN  += __shfl_down(accN, o2);
    accGX += __shfl_down(accGX, o2);
    accGY += __shfl_down(accGY, o2);
  }
  if (lane == 0) { redN[wv] = accN; redGX[wv] = accGX; redGY[wv] = accGY; }
  __syncthreads();
  if (j == 0) {
    float n = 0.f, gx = 0.f, gy = 0.f;
#pragma unroll
    for (int w2 = 0; w2 < 8; ++w2) { n += redN[w2]; gx += redGX[w2]; gy += redGY[w2]; }
    double* p = partial + (size_t)blk * 3;
    p[0] = (double)n; p[1] = (double)gx; p[2] = (double)gy;
  }
}

__global__ __launch_bounds__(64) void ktv_reduce(const double* __restrict__ partial,
                                                 float* __restrict__ out) {
  double n = 0.0, gx = 0.0, gy = 0.0;
  for (int i = threadIdx.x; i < NBLOCKS; i += 64) {
    const double* p = partial + (size_t)i * 3;
    n += p[0]; gx += p[1]; gy += p[2];
  }
#pragma unroll
  for (int o2 = 32; o2 > 0; o2 >>= 1) {
    n  += __shfl_down(n, o2);
    gx += __shfl_down(gx, o2);
    gy += __shfl_down(gy, o2);
  }
  if (threadIdx.x == 0) {
    const double norm_loss = n / 6060144.0;          // 24*502*503
    const double grad_loss = (gx + gy) / 6279168.0;  // 24*511*512
    out[0] = (float)(1e-4 * norm_loss + grad_loss);
  }
}

extern "C" void kernel_launch(void* const* d_in, const int* in_sizes, int n_in,
                              void* d_out, int out_size, void* d_ws, size_t ws_size,
                              hipStream_t stream) {
  (void)in_sizes; (void)n_in; (void)out_size; (void)ws_size;
  const float* L = (const float*)d_in[0];
  const float* R = (const float*)d_in[1];
  const float* I = (const float*)d_in[2];
  double* partial = (double*)d_ws;   // NBLOCKS*3 doubles = 12096 B
  float* out = (float*)d_out;

  hipLaunchKernelGGL(ktv_main, dim3(NBLOCKS), dim3(512), 0, stream, L, R, I, partial);
  hipLaunchKernelGGL(ktv_reduce, dim3(1), dim3(64), 0, stream, partial, out);
}